// Round 15
// baseline (114.404 us; speedup 1.0000x reference)
//
#include <hip/hip_runtime.h>

#define NB 32
#define NN 2048
#define ND 128
#define NSUP 2032
#define KKEEP 1016
#define MM 1032
#define SEG 254              // NSUP / 8 segments per batch

typedef unsigned long long u64;
typedef unsigned int u32;
typedef float f32x4 __attribute__((ext_vector_type(4)));   // clang-native vec4

// Opaque IEEE f32 RN ops — compiler cannot contract/reassociate these.
__device__ __forceinline__ float mulrn(float a, float b) {
  float r;
  asm("v_mul_f32 %0, %1, %2" : "=v"(r) : "v"(a), "v"(b));
  return r;
}
__device__ __forceinline__ float addrn(float a, float b) {
  float r;
  asm("v_add_f32 %0, %1, %2" : "=v"(r) : "v"(a), "v"(b));
  return r;
}
// Single-rounded FMA — matches x86 vfmadd exactly.
__device__ __forceinline__ float fmarn(float a, float b, float c) {
  float r;
  asm("v_fma_f32 %0, %1, %2, %3" : "=v"(r) : "v"(a), "v"(b), "v"(c));
  return r;
}

// ---------------------------------------------------------------------------
// K1: bit-exact JAX/XLA-CPU f32 score (VERIFIED round 10 — do not change):
//   W16 single-accumulator chain with SEPARATE mul/add, halving-tree reduce,
//   CR f32 div by 100, Eigen/Cephes pexp Horner (m=0 regime), 1/(1+e) CR div.
//   KEY = f32 score bits (ref's ulp-ties preserved) | row idx (stable ties).
// ---------------------------------------------------------------------------
__global__ __launch_bounds__(256) void k_score(const float* __restrict__ X,
                                               const float* __restrict__ w,
                                               const float* __restrict__ bias,
                                               u64* __restrict__ keys,
                                               float* __restrict__ score) {
#pragma clang fp contract(off)
  int row = blockIdx.x * 256 + threadIdx.x;
  if (row >= NB * NN) return;
  const float* x = X + (size_t)row * ND;

  float l[16];
  #pragma unroll
  for (int k = 0; k < 16; ++k) l[k] = 0.f;
  #pragma unroll
  for (int step = 0; step < 8; ++step) {
    const float* xp = x + step * 16;
    const float* wp = w + step * 16;
    #pragma unroll
    for (int q4 = 0; q4 < 4; ++q4) {
      const float4 xv = *reinterpret_cast<const float4*>(xp + q4 * 4);
      const float4 wv = *reinterpret_cast<const float4*>(wp + q4 * 4);
      l[q4 * 4 + 0] = addrn(mulrn(xv.x, wv.x), l[q4 * 4 + 0]);
      l[q4 * 4 + 1] = addrn(mulrn(xv.y, wv.y), l[q4 * 4 + 1]);
      l[q4 * 4 + 2] = addrn(mulrn(xv.z, wv.z), l[q4 * 4 + 2]);
      l[q4 * 4 + 3] = addrn(mulrn(xv.w, wv.w), l[q4 * 4 + 3]);
    }
  }
  #pragma unroll
  for (int k = 0; k < 8; ++k) l[k] = addrn(l[k], l[k + 8]);
  #pragma unroll
  for (int k = 0; k < 4; ++k) l[k] = addrn(l[k], l[k + 4]);
  l[0] = addrn(l[0], l[2]);
  l[1] = addrn(l[1], l[3]);
  const float dot = addrn(l[0], l[1]);

  const float z = __fdiv_rn(addrn(dot, bias[0]), 100.0f);

  const float xe = -z;
  const float z2 = mulrn(xe, xe);
  float y = fmarn(1.9875691500E-4f, xe, 1.3981999507E-3f);
  y = fmarn(y, xe, 8.3334519073E-3f);
  y = fmarn(y, xe, 4.1665795894E-2f);
  y = fmarn(y, xe, 1.6666665459E-1f);
  y = fmarn(y, xe, 5.0000001201E-1f);
  y = fmarn(y, z2, xe);
  const float e = addrn(y, 1.0f);

  const float s = __fdiv_rn(1.0f, addrn(1.0f, e));

  score[row] = s;

  const u32 sb = __float_as_uint(s);   // s>0 -> bits ascending-sortable
  const int n = row & (NN - 1);
  keys[row] = ((u64)sb << 32) | (u32)n;
}

// ---------------------------------------------------------------------------
// K2 v3: rank-by-counting selection (VERIFIED round 14): rank == output
//   position under (score_bits | idx) ascending; rank < 1016 = selected.
// ---------------------------------------------------------------------------
__global__ __launch_bounds__(256) void k_rank(const u64* __restrict__ keys,
                                              const float* __restrict__ score,
                                              int* __restrict__ idxs,
                                              float* __restrict__ vals,
                                              float* __restrict__ out_idx) {
  __shared__ u64 lk[NSUP];   // 16.3 KiB
  const int b   = blockIdx.x >> 3;
  const int seg = blockIdx.x & 7;
  const int t   = threadIdx.x;
  const size_t bNN = (size_t)b * NN;
  const int    bMM = b * MM;

  for (int i = t; i < NSUP; i += 256) lk[i] = keys[bNN + i];
  __syncthreads();

  if (t < SEG) {
    const int e  = seg * SEG + t;
    const u64 my = lk[e];
    int cnt = 0;
    #pragma unroll 4
    for (int s = 0; s < NSUP; s += 4) {
      const u64 k0 = lk[s], k1 = lk[s + 1], k2 = lk[s + 2], k3 = lk[s + 3];
      cnt += (int)(k0 < my) + (int)(k1 < my) + (int)(k2 < my) + (int)(k3 < my);
    }
    if (cnt < KKEEP) {
      idxs[bMM + cnt]    = e;
      vals[bMM + cnt]    = score[bNN + e];
      out_idx[bMM + cnt] = (float)e;
    }
  } else {
    const int q   = seg * 2 + (t - SEG);   // 0..15
    const int e   = NSUP + q;
    const int pos = KKEEP + q;
    idxs[bMM + pos]    = e;
    vals[bMM + pos]    = score[bNN + e];
    out_idx[bMM + pos] = (float)e;
  }
}

// ---------------------------------------------------------------------------
// K4 v3: TWO output rows per 256-thread block (4 waves). 16 KB of A-row
//   loads issued before one barrier (2x in-flight read bytes vs v2);
//   8 blocks/CU x 4 waves = 32 waves/CU (max). Column indices read as int4
//   straight from global (4 KB/batch, shared by 516 blocks -> L2-hot).
//   Nontemporal A loads and new_A stores (single-use streams).
// ---------------------------------------------------------------------------
__global__ __launch_bounds__(256) void k_newa(const float* __restrict__ A,
                                              const float* __restrict__ X,
                                              const int* __restrict__ idxs,
                                              const float* __restrict__ vals,
                                              float* __restrict__ out_a,
                                              float* __restrict__ out_x) {
  __shared__ float srow[2][NN];  // 16 KiB
  const int t    = threadIdx.x;
  const int row0 = blockIdx.x * 2;          // rows row0, row0+1 (same batch)
  const int b    = row0 / MM;
  const int* cols = idxs + b * MM;

  const int ri0 = idxs[row0];
  const int ri1 = idxs[row0 + 1];
  const float* ar0 = A + ((size_t)b * NN + ri0) * NN;
  const float* ar1 = A + ((size_t)b * NN + ri1) * NN;

  // stage both rows: 2 x 512 f32x4 over 256 threads = 2 each per row
  #pragma unroll
  for (int i = 0; i < 2; ++i) {
    const int off = (t + i * 256) * 4;
    *reinterpret_cast<f32x4*>(&srow[0][off]) =
        __builtin_nontemporal_load(reinterpret_cast<const f32x4*>(ar0 + off));
    *reinterpret_cast<f32x4*>(&srow[1][off]) =
        __builtin_nontemporal_load(reinterpret_cast<const f32x4*>(ar1 + off));
  }

  // fused new_X: wave0 lanes 0-31 -> row0, wave2 lanes 0-31 -> row1
  const int xr = (t < 32) ? 0 : (t >= 128 && t < 160) ? 1 : -1;
  if (xr >= 0) {
    const int r  = row0 + xr;
    const int ri = xr ? ri1 : ri0;
    const float v = vals[r];
    const float4 xv = reinterpret_cast<const float4*>(
        X + ((size_t)b * NN + ri) * ND)[t & 31];
    float4 o = make_float4(xv.x * v, xv.y * v, xv.z * v, xv.w * v);
    reinterpret_cast<float4*>(out_x + (size_t)r * ND)[t & 31] = o;
  }
  __syncthreads();

  // gather: threads 0-127 -> row0, 128-255 -> row1 (258 f32x4 per row)
  const int half = t >> 7;
  const int tl   = t & 127;
  const float* sr = srow[half];
  f32x4* orow = reinterpret_cast<f32x4*>(out_a + (size_t)(row0 + half) * MM);
  for (int c = tl; c < MM / 4; c += 128) {
    const int4 j4 = reinterpret_cast<const int4*>(cols)[c];   // L2-hot
    f32x4 o;
    o.x = sr[j4.x];
    o.y = sr[j4.y];
    o.z = sr[j4.z];
    o.w = sr[j4.w];
    __builtin_nontemporal_store(o, orow + c);
  }
}

extern "C" void kernel_launch(void* const* d_in, const int* in_sizes, int n_in,
                              void* d_out, int out_size, void* d_ws, size_t ws_size,
                              hipStream_t stream) {
  const float* A    = (const float*)d_in[0];   // [32,2048,2048]
  const float* X    = (const float*)d_in[1];   // [32,2048,128]
  const float* w    = (const float*)d_in[2];   // [128]
  const float* bias = (const float*)d_in[3];   // [1]

  float* out0 = (float*)d_out;                          // new_A
  float* out1 = out0 + (size_t)NB * MM * MM;            // new_X
  float* out2 = out1 + (size_t)NB * MM * ND;            // idx (as f32)

  u64*   keys  = (u64*)d_ws;                 // [32][2048] u64
  float* score = (float*)(keys + NB * NN);   // [32][2048] f32
  int*   idxs  = (int*)(score + NB * NN);    // [32][1032] i32
  float* vals  = (float*)(idxs + NB * MM);   // [32][1032] f32

  hipLaunchKernelGGL(k_score, dim3(NB * NN / 256), dim3(256), 0, stream, X, w, bias, keys, score);
  hipLaunchKernelGGL(k_rank,  dim3(NB * 8),        dim3(256), 0, stream, keys, score, idxs, vals, out2);
  hipLaunchKernelGGL(k_newa,  dim3(NB * MM / 2),   dim3(256), 0, stream, A, X, idxs, vals, out0, out1);
}